// Round 5
// baseline (372.664 us; speedup 1.0000x reference)
//
#include <hip/hip_runtime.h>
#include <math.h>

#define N_ 30000
#define K_ 15
#define T_ 400
#define NC_ 5
#define TQ (T_ / 4)    // 100 float4 per row
#define TH (T_ / 8)    // 50 half8 per row
#define TS (T_ / 16)   // 25 fp8x16 (u32x4) per row

typedef float f4 __attribute__((ext_vector_type(4)));
typedef float f2 __attribute__((ext_vector_type(2)));
typedef _Float16 h4 __attribute__((ext_vector_type(4)));
typedef _Float16 h8 __attribute__((ext_vector_type(8)));
typedef unsigned int u32x4 __attribute__((ext_vector_type(4)));

static constexpr float TWO_PI_F = 6.283185307179586f;
static constexpr float SMOOTH_F = 0.2f;

// ---- Pass A: fp16 row (for own term) + fp8 e4m3 row (for gather) -----------
__global__ __launch_bounds__(256) void emd_sum_kernel(
    const float* __restrict__ emd, _Float16* __restrict__ out_h,
    unsigned int* __restrict__ out_q) {
  int g = blockIdx.x * blockDim.x + threadIdx.x;          // over N_*TQ
  if (g >= N_ * TQ) return;
  int n = g / TQ;
  int j = g - n * TQ;
  const f4* row = (const f4*)(emd + (size_t)n * 4 * T_);
  f4 a = __builtin_nontemporal_load(&row[j]);
  f4 b = __builtin_nontemporal_load(&row[j + TQ]);
  f4 c = __builtin_nontemporal_load(&row[j + 2 * TQ]);
  f4 d = __builtin_nontemporal_load(&row[j + 3 * TQ]);
  f4 s = a + b + c + d;
  h4 o = {(_Float16)s.x, (_Float16)s.y, (_Float16)s.z, (_Float16)s.w};
  ((h4*)out_h)[g] = o;
  int q = __builtin_amdgcn_cvt_pk_fp8_f32(s.x, s.y, 0, false);
  q = __builtin_amdgcn_cvt_pk_fp8_f32(s.z, s.w, q, true);
  out_q[g] = (unsigned int)q;
}

// ---- Pass B1: smoothed residual params, one (n,c) per thread ---------------
__global__ __launch_bounds__(256) void params_kernel(
    const int* __restrict__ idx, const float* __restrict__ nw,
    const float* __restrict__ amps, const float* __restrict__ phases,
    float* __restrict__ amp_s, float* __restrict__ ph_s) {
  int g = blockIdx.x * blockDim.x + threadIdx.x;          // over N_*NC_
  if (g >= N_ * NC_) return;
  int n = g / NC_;
  int c = g - n * NC_;
  float asum = 0.f, ssum = 0.f, csum = 0.f;
#pragma unroll
  for (int k = 0; k < K_; k++) {
    int id = idx[n * K_ + k];
    float w = nw[n * K_ + k];
    asum += w * amps[id * NC_ + c];
    float p = phases[id * NC_ + c];
    ssum += w * __sinf(p);
    csum += w * __cosf(p);
  }
  amp_s[g] = (1.f - SMOOTH_F) * amps[g] + SMOOTH_F * asum;
  ph_s[g] = (1.f - SMOOTH_F) * phases[g] + SMOOTH_F * atan2f(ssum, csum);
}

// ---- Pass B2: combined gather weights, one (n,k) per thread ----------------
__global__ __launch_bounds__(256) void cw_kernel(
    const float* __restrict__ nw, const float* __restrict__ lw,
    const float* __restrict__ esw, const float* __restrict__ lsw,
    float* __restrict__ cw, float* __restrict__ c_own) {
  int g = blockIdx.x * blockDim.x + threadIdx.x;          // over N_*K_
  if (g >= N_ * K_) return;
  int n = g / K_;
  float ew = 1.f / (1.f + __expf(-esw[n]));
  float lwb = 1.f / (1.f + __expf(-lsw[n]));
  cw[g] = ew * (lwb * lw[g] + (1.f - lwb) * nw[g]);
  if (g - n * K_ == 0) c_own[n] = 1.f - ew;
}

// ---- Pass C: fp8 gather (16B/neighbor) + fp16 own + harmonics --------------
__global__ __launch_bounds__(256) void main_kernel(
    const u32x4* __restrict__ emd_q4, const h8* __restrict__ emd_h8,
    const f4* __restrict__ tvec4, const int* __restrict__ idx,
    const float* __restrict__ cw, const float* __restrict__ c_own,
    const float* __restrict__ offset, const float* __restrict__ trend,
    const float* __restrict__ amp_s, const float* __restrict__ ph_s,
    const float* __restrict__ periods, f4* __restrict__ out4) {
  int g = blockIdx.x * blockDim.x + threadIdx.x;          // over N_*TS
  if (g >= N_ * TS) return;
  int n = g / TS;
  int j = g - n * TS;
  const int base = n * K_;

  float acc[16];
#pragma unroll
  for (int i = 0; i < 16; i++) acc[i] = 0.f;

#pragma unroll
  for (int k = 0; k < K_; k++) {
    int id = idx[base + k];
    float w = cw[base + k];
    u32x4 v = emd_q4[(size_t)id * TS + j];
    f2 p;
    p = __builtin_amdgcn_cvt_pk_f32_fp8(v.x, false); acc[0] += w * p.x;  acc[1] += w * p.y;
    p = __builtin_amdgcn_cvt_pk_f32_fp8(v.x, true);  acc[2] += w * p.x;  acc[3] += w * p.y;
    p = __builtin_amdgcn_cvt_pk_f32_fp8(v.y, false); acc[4] += w * p.x;  acc[5] += w * p.y;
    p = __builtin_amdgcn_cvt_pk_f32_fp8(v.y, true);  acc[6] += w * p.x;  acc[7] += w * p.y;
    p = __builtin_amdgcn_cvt_pk_f32_fp8(v.z, false); acc[8] += w * p.x;  acc[9] += w * p.y;
    p = __builtin_amdgcn_cvt_pk_f32_fp8(v.z, true);  acc[10] += w * p.x; acc[11] += w * p.y;
    p = __builtin_amdgcn_cvt_pk_f32_fp8(v.w, false); acc[12] += w * p.x; acc[13] += w * p.y;
    p = __builtin_amdgcn_cvt_pk_f32_fp8(v.w, true);  acc[14] += w * p.x; acc[15] += w * p.y;
  }

  h8 own0 = emd_h8[(size_t)n * TH + 2 * j];
  h8 own1 = emd_h8[(size_t)n * TH + 2 * j + 1];
  float co = c_own[n];
  float off = offset[n];
  float tr = trend[n];

  float amp[NC_], ph[NC_], omg[NC_];
#pragma unroll
  for (int c = 0; c < NC_; c++) {
    amp[c] = amp_s[n * NC_ + c];
    ph[c] = ph_s[n * NC_ + c];
    float per = fminf(fmaxf(periods[c], 15.f), 350.f);
    omg[c] = TWO_PI_F / per;
  }

  f4 tf[4];
#pragma unroll
  for (int q = 0; q < 4; q++) tf[q] = tvec4[4 * j + q];

#pragma unroll
  for (int q = 0; q < 4; q++) {
    f4 r;
#pragma unroll
    for (int e = 0; e < 4; e++) {
      int i = 4 * q + e;
      float t = tf[q][e];
      float ownv = (float)(i < 8 ? own0[i] : own1[i - 8]);
      float rr = off + tr * t + co * ownv + acc[i];
#pragma unroll
      for (int c = 0; c < NC_; c++) rr += amp[c] * __sinf(omg[c] * t + ph[c]);
      r[e] = rr;
    }
    __builtin_nontemporal_store(r, &out4[4 * g + q]);
  }
}

// ---- Fallback: fully fused, no workspace -----------------------------------
__global__ __launch_bounds__(256) void fused_kernel(
    const float* __restrict__ tvec, const float* __restrict__ offset,
    const float* __restrict__ trend, const float* __restrict__ emd,
    const int* __restrict__ idx, const float* __restrict__ nw,
    const float* __restrict__ lw, const float* __restrict__ amps,
    const float* __restrict__ phases, const float* __restrict__ periods,
    const float* __restrict__ esw, const float* __restrict__ lsw,
    float* __restrict__ out) {
  int n = blockIdx.x;
  int tid = threadIdx.x;
  __shared__ int sidx[K_];
  __shared__ float snw[K_], slw[K_];
  __shared__ float samp[NC_], sph[NC_], somega[NC_];
  __shared__ float s_off, s_tr, s_ew, s_lw;
  if (tid < K_) {
    sidx[tid] = idx[n * K_ + tid];
    snw[tid] = nw[n * K_ + tid];
    slw[tid] = lw[n * K_ + tid];
  }
  __syncthreads();
  if (tid < NC_) {
    int c = tid;
    float asum = 0.f, ssum = 0.f, csum = 0.f;
    for (int k = 0; k < K_; k++) {
      int j = sidx[k];
      float w = snw[k];
      asum += w * amps[j * NC_ + c];
      float p = phases[j * NC_ + c];
      ssum += w * __sinf(p);
      csum += w * __cosf(p);
    }
    samp[c] = (1.f - SMOOTH_F) * amps[n * NC_ + c] + SMOOTH_F * asum;
    sph[c] = (1.f - SMOOTH_F) * phases[n * NC_ + c] + SMOOTH_F * atan2f(ssum, csum);
    float per = fminf(fmaxf(periods[c], 15.f), 350.f);
    somega[c] = TWO_PI_F / per;
  } else if (tid == 64) {
    s_off = offset[n];
    s_tr = trend[n];
    s_ew = 1.f / (1.f + __expf(-esw[n]));
    s_lw = 1.f / (1.f + __expf(-lsw[n]));
  }
  __syncthreads();
  float ew = s_ew, lww = s_lw;
  for (int t = tid; t < T_; t += 256) {
    const float* rown = emd + (size_t)n * 4 * T_ + t;
    float own = rown[0] + rown[T_] + rown[2 * T_] + rown[3 * T_];
    float lsum = 0.f, rsum = 0.f;
#pragma unroll
    for (int k = 0; k < K_; k++) {
      const float* rk = emd + (size_t)sidx[k] * 4 * T_ + t;
      float v = rk[0] + rk[T_] + rk[2 * T_] + rk[3 * T_];
      lsum += slw[k] * v;
      rsum += snw[k] * v;
    }
    float adjusted = (1.f - ew) * own + ew * lww * lsum + ew * (1.f - lww) * rsum;
    float tf = tvec[t];
    float res = 0.f;
#pragma unroll
    for (int c = 0; c < NC_; c++) res += samp[c] * __sinf(somega[c] * tf + sph[c]);
    out[(size_t)n * T_ + t] = s_off + s_tr * tf + adjusted + res;
  }
}

extern "C" void kernel_launch(void* const* d_in, const int* in_sizes, int n_in,
                              void* d_out, int out_size, void* d_ws, size_t ws_size,
                              hipStream_t stream) {
  const float* tvec    = (const float*)d_in[0];
  const float* offset  = (const float*)d_in[1];
  const float* trend   = (const float*)d_in[2];
  const float* emd     = (const float*)d_in[3];
  const int*   idx     = (const int*)d_in[4];
  const float* nw      = (const float*)d_in[5];
  const float* lw      = (const float*)d_in[6];
  const float* amps    = (const float*)d_in[7];
  const float* phases  = (const float*)d_in[8];
  const float* periods = (const float*)d_in[9];
  const float* esw     = (const float*)d_in[10];
  const float* lsw     = (const float*)d_in[11];
  float* out = (float*)d_out;

  const size_t emd_h_bytes = (size_t)N_ * T_ * sizeof(_Float16);  // 24 MB
  const size_t emd_q_bytes = (size_t)N_ * T_;                     // 12 MB
  const size_t par_bytes = (size_t)N_ * NC_ * sizeof(float);      // 600 KB
  const size_t cw_bytes = (size_t)N_ * K_ * sizeof(float);        // 1.8 MB
  const size_t n_bytes = (size_t)N_ * sizeof(float);              // 120 KB
  const size_t need = emd_h_bytes + emd_q_bytes + 2 * par_bytes + cw_bytes + n_bytes;

  if (ws_size >= need) {
    char* p = (char*)d_ws;
    _Float16* emd_h   = (_Float16*)p;     p += emd_h_bytes;
    unsigned int* emd_q = (unsigned int*)p; p += emd_q_bytes;
    float* amp_s      = (float*)p;        p += par_bytes;
    float* ph_s       = (float*)p;        p += par_bytes;
    float* cw         = (float*)p;        p += cw_bytes;
    float* c_own      = (float*)p;        p += n_bytes;

    emd_sum_kernel<<<(N_ * TQ + 255) / 256, 256, 0, stream>>>(emd, emd_h, emd_q);
    params_kernel<<<(N_ * NC_ + 255) / 256, 256, 0, stream>>>(
        idx, nw, amps, phases, amp_s, ph_s);
    cw_kernel<<<(N_ * K_ + 255) / 256, 256, 0, stream>>>(
        nw, lw, esw, lsw, cw, c_own);
    main_kernel<<<(N_ * TS + 255) / 256, 256, 0, stream>>>(
        (const u32x4*)emd_q, (const h8*)emd_h, (const f4*)tvec, idx, cw, c_own,
        offset, trend, amp_s, ph_s, periods, (f4*)out);
  } else {
    fused_kernel<<<N_, 256, 0, stream>>>(tvec, offset, trend, emd, idx, nw, lw,
                                         amps, phases, periods, esw, lsw, out);
  }
}